// Round 1
// baseline (618.034 us; speedup 1.0000x reference)
//
#include <hip/hip_runtime.h>
#include <math.h>

#define BB   4096
#define SS   5
#define DD   64
#define HSZ  961
#define VSA  1024
#define NT   256
#define KPT  4      // VSA / NT
#define LNE  1e-3f

__device__ __forceinline__ float silu_f(float x) { return x / (1.f + __expf(-x)); }
__device__ __forceinline__ float sgn_f(float x)  { return (x > 0.f) ? 1.f : ((x < 0.f) ? -1.f : 0.f); }

// ---------------- Kernel 1: sp = LN(silu(conv(symbols, h))) ----------------
// symbols is batch-independent -> compute the [S, VSA] tensor once into ws.
__global__ __launch_bounds__(NT)
void sp_kernel(const float* __restrict__ symbols, const float* __restrict__ h,
               const float* __restrict__ gamma, const float* __restrict__ beta,
               float* __restrict__ sp)
{
    __shared__ float hbuf[HSZ];
    __shared__ float xbuf[DD];
    __shared__ float red[16];
    const int s = blockIdx.x;
    const int tid = threadIdx.x;

    for (int i = tid; i < HSZ; i += NT) hbuf[i] = h[s * HSZ + i];
    if (tid < DD) xbuf[tid] = symbols[s * DD + tid];
    __syncthreads();

    float ys[KPT];
    float lsum = 0.f, lsq = 0.f;
    for (int k = 0; k < KPT; k++) {
        const int t = tid + NT * k;
        int dlo = t - (HSZ - 1); if (dlo < 0) dlo = 0;
        int dhi = t;             if (dhi > DD - 1) dhi = DD - 1;
        float acc = 0.f;
        for (int d = dlo; d <= dhi; d++)
            acc += xbuf[d] * hbuf[HSZ - 1 + d - t];
        const float y = silu_f(acc);
        ys[k] = y; lsum += y; lsq += y * y;
    }
    for (int off = 32; off; off >>= 1) {
        lsum += __shfl_down(lsum, off, 64);
        lsq  += __shfl_down(lsq,  off, 64);
    }
    const int wave = tid >> 6, lane = tid & 63;
    if (lane == 0) { red[wave * 2] = lsum; red[wave * 2 + 1] = lsq; }
    __syncthreads();
    if (tid == 0) {
        float s0 = 0.f, s1 = 0.f;
        for (int w = 0; w < NT / 64; w++) { s0 += red[w * 2]; s1 += red[w * 2 + 1]; }
        const float mean = s0 / VSA;
        const float var  = s1 / VSA - mean * mean;
        red[8] = mean; red[9] = rsqrtf(var + LNE);
    }
    __syncthreads();
    const float mean = red[8], rstd = red[9];
    for (int k = 0; k < KPT; k++) {
        const int t = tid + NT * k;
        sp[s * VSA + t] = (ys[k] - mean) * rstd * gamma[t] + beta[t];
    }
}

// ---------------- Kernel 2: per-batch fused pipeline ----------------
// one block per b: conv+silu+LN -> vp (LDS), sign-scores, softmax, attention
// combine, final silu, store. No [B,S,VSA] intermediate hits HBM.
__global__ __launch_bounds__(NT)
void main_kernel(const float* __restrict__ values, const float* __restrict__ h,
                 const float* __restrict__ sp, const float* __restrict__ gamma,
                 const float* __restrict__ beta, float* __restrict__ out)
{
    __shared__ float hbuf[SS][HSZ];     // 19.2 KB
    __shared__ float xbuf[SS][DD];      //  1.3 KB
    __shared__ float vpbuf[SS][VSA];    // 20.5 KB
    __shared__ float spbuf[SS][VSA];    // 20.5 KB
    __shared__ float red[16];
    __shared__ float scorered[4][SS * SS];
    __shared__ float scorebuf[SS * SS];
    __shared__ float wbuf[SS * SS];

    const int b = blockIdx.x;
    const int tid = threadIdx.x;

    for (int i = tid; i < SS * HSZ; i += NT) (&hbuf[0][0])[i] = h[i];
    for (int i = tid; i < SS * DD;  i += NT) (&xbuf[0][0])[i] = values[(size_t)b * SS * DD + i];
    for (int i = tid; i < SS * VSA; i += NT) (&spbuf[0][0])[i] = sp[i];
    __syncthreads();

    // conv + silu + LayerNorm per seq position s
    for (int s = 0; s < SS; s++) {
        float ys[KPT];
        float lsum = 0.f, lsq = 0.f;
        for (int k = 0; k < KPT; k++) {
            const int t = tid + NT * k;
            int dlo = t - (HSZ - 1); if (dlo < 0) dlo = 0;
            int dhi = t;             if (dhi > DD - 1) dhi = DD - 1;
            float acc = 0.f;
            for (int d = dlo; d <= dhi; d++)
                acc += xbuf[s][d] * hbuf[s][HSZ - 1 + d - t];
            const float y = silu_f(acc);
            ys[k] = y; lsum += y; lsq += y * y;
        }
        for (int off = 32; off; off >>= 1) {
            lsum += __shfl_down(lsum, off, 64);
            lsq  += __shfl_down(lsq,  off, 64);
        }
        const int wave = tid >> 6, lane = tid & 63;
        if (lane == 0) { red[wave * 2] = lsum; red[wave * 2 + 1] = lsq; }
        __syncthreads();
        if (tid == 0) {
            float s0 = 0.f, s1 = 0.f;
            for (int w = 0; w < 4; w++) { s0 += red[w * 2]; s1 += red[w * 2 + 1]; }
            const float mean = s0 / VSA;
            const float var  = s1 / VSA - mean * mean;
            red[8] = mean; red[9] = rsqrtf(var + LNE);
        }
        __syncthreads();
        const float mean = red[8], rstd = red[9];
        for (int k = 0; k < KPT; k++) {
            const int t = tid + NT * k;
            vpbuf[s][t] = (ys[k] - mean) * rstd * gamma[t] + beta[t];
        }
        __syncthreads();
    }

    // scores[j][i] = mean_t sign(vp[i][t]) * sign(vp[i][t] + sp[j][t])
    float acc25[SS * SS];
    for (int p = 0; p < SS * SS; p++) acc25[p] = 0.f;
    for (int k = 0; k < KPT; k++) {
        const int t = tid + NT * k;
        float vi[SS], sj[SS];
        for (int i = 0; i < SS; i++) { vi[i] = vpbuf[i][t]; sj[i] = spbuf[i][t]; }
        for (int j = 0; j < SS; j++) {
            const float sjt = sj[j];
            for (int i = 0; i < SS; i++)
                acc25[j * SS + i] += sgn_f(vi[i]) * sgn_f(vi[i] + sjt);
        }
    }
    for (int off = 32; off; off >>= 1)
        for (int p = 0; p < SS * SS; p++)
            acc25[p] += __shfl_down(acc25[p], off, 64);
    {
        const int wave = tid >> 6, lane = tid & 63;
        if (lane == 0)
            for (int p = 0; p < SS * SS; p++) scorered[wave][p] = acc25[p];
    }
    __syncthreads();
    if (tid < SS * SS) {
        const float sv = scorered[0][tid] + scorered[1][tid] + scorered[2][tid] + scorered[3][tid];
        scorebuf[tid] = sv * (1.f / VSA);
    }
    __syncthreads();

    // softmax over i (size 5) per row j — 5 threads do it
    if (tid < SS) {
        const int j = tid;
        float m = -1e30f;
        for (int i = 0; i < SS; i++) m = fmaxf(m, scorebuf[j * SS + i]);
        float e[SS], ssum = 0.f;
        for (int i = 0; i < SS; i++) { e[i] = __expf(scorebuf[j * SS + i] - m); ssum += e[i]; }
        const float inv = 1.f / ssum;
        for (int i = 0; i < SS; i++) wbuf[j * SS + i] = e[i] * inv;
    }
    __syncthreads();

    // out[b][j][t] = silu( (sum_i w[j][i] * vp[i][t]) * sp[j][t] )
    const size_t base = (size_t)b * SS * VSA;
    for (int j = 0; j < SS; j++) {
        for (int k = 0; k < KPT; k++) {
            const int t = tid + NT * k;
            float att = 0.f;
            for (int i = 0; i < SS; i++) att += wbuf[j * SS + i] * vpbuf[i][t];
            const float v = att * spbuf[j][t];
            out[base + j * VSA + t] = silu_f(v);
        }
    }
}

extern "C" void kernel_launch(void* const* d_in, const int* in_sizes, int n_in,
                              void* d_out, int out_size, void* d_ws, size_t ws_size,
                              hipStream_t stream) {
    const float* values  = (const float*)d_in[0];
    const float* h       = (const float*)d_in[1];
    const float* symbols = (const float*)d_in[2];
    const float* gamma   = (const float*)d_in[3];
    const float* beta    = (const float*)d_in[4];
    float* out = (float*)d_out;
    float* sp  = (float*)d_ws;   // S*VSA floats = 20 KB

    sp_kernel<<<SS, NT, 0, stream>>>(symbols, h, gamma, beta, sp);
    main_kernel<<<BB, NT, 0, stream>>>(values, h, sp, gamma, beta, out);
}

// Round 2
// 230.074 us; speedup vs baseline: 2.6862x; 2.6862x over previous
//
#include <hip/hip_runtime.h>
#include <math.h>

#define BB   4096
#define SS   5
#define DD   64
#define HSZ  961
#define VSA  1024
#define NT   256
#define LNE  1e-3f

// padded h layout: P[r] = h[r-POFF] for r in [POFF, POFF+960], else 0
#define POFF 64
#define PW   1092   // max index accessed = 1091 (tid=0, chunk 15, +7)

__device__ __forceinline__ float silu_f(float x) { return x / (1.f + __expf(-x)); }

// Register-blocked conv for 4 consecutive outputs t = 4*tid+j.
// acc[j] = sum_d x[d] * P[1024 + d - 4*tid - j]; chunked over d by 4 with a
// sliding 8-reg window; one aligned ds_read_b128 per chunk.
__device__ __forceinline__ void conv4(const float* __restrict__ xp,  // 64 uniform floats
                                      const float* hpad,             // LDS, PW floats
                                      int tid, float acc[4])
{
    const int base = 1020 - 4 * tid;           // A_0, multiple of 4 -> 16B aligned
    float hw[8];
    *(float4*)&hw[0] = *(const float4*)&hpad[base];
    acc[0] = acc[1] = acc[2] = acc[3] = 0.f;
#pragma unroll
    for (int c = 0; c < 16; c++) {
        *(float4*)&hw[4] = *(const float4*)&hpad[base + 4 * (c + 1)];
        const float x0 = xp[4 * c + 0];
        const float x1 = xp[4 * c + 1];
        const float x2 = xp[4 * c + 2];
        const float x3 = xp[4 * c + 3];
        acc[0] += x0 * hw[4]; acc[0] += x1 * hw[5]; acc[0] += x2 * hw[6]; acc[0] += x3 * hw[7];
        acc[1] += x0 * hw[3]; acc[1] += x1 * hw[4]; acc[1] += x2 * hw[5]; acc[1] += x3 * hw[6];
        acc[2] += x0 * hw[2]; acc[2] += x1 * hw[3]; acc[2] += x2 * hw[4]; acc[2] += x3 * hw[5];
        acc[3] += x0 * hw[1]; acc[3] += x1 * hw[2]; acc[3] += x2 * hw[3]; acc[3] += x3 * hw[4];
        hw[0] = hw[4]; hw[1] = hw[5]; hw[2] = hw[6]; hw[3] = hw[7];
    }
}

// ---------------- Kernel 1: sp = LN(silu(conv(symbols, h))) ----------------
__global__ __launch_bounds__(NT)
void sp_kernel(const float* __restrict__ symbols, const float* __restrict__ h,
               const float* __restrict__ gamma, const float* __restrict__ beta,
               float* __restrict__ sp)
{
    __shared__ float hpad[PW];
    __shared__ float red[4][2];
    const int s = blockIdx.x;
    const int tid = threadIdx.x;
    const int lane = tid & 63, wave = tid >> 6;

    for (int r = tid; r < PW; r += NT)
        hpad[r] = (r >= POFF && r <= POFF + 960) ? h[s * HSZ + (r - POFF)] : 0.f;
    __syncthreads();

    float acc[4];
    conv4(symbols + s * DD, hpad, tid, acc);

    float ys[4];
    float lsum = 0.f, lsq = 0.f;
#pragma unroll
    for (int j = 0; j < 4; j++) {
        ys[j] = silu_f(acc[j]);
        lsum += ys[j]; lsq += ys[j] * ys[j];
    }
#pragma unroll
    for (int off = 32; off; off >>= 1) {
        lsum += __shfl_down(lsum, off, 64);
        lsq  += __shfl_down(lsq,  off, 64);
    }
    if (lane == 0) { red[wave][0] = lsum; red[wave][1] = lsq; }
    __syncthreads();
    float s0 = 0.f, s1 = 0.f;
#pragma unroll
    for (int w = 0; w < 4; w++) { s0 += red[w][0]; s1 += red[w][1]; }
    const float mean = s0 * (1.f / VSA);
    const float rstd = rsqrtf(s1 * (1.f / VSA) - mean * mean + LNE);

    const float4 g4 = *(const float4*)&gamma[4 * tid];
    const float4 b4 = *(const float4*)&beta[4 * tid];
    float4 o;
    o.x = (ys[0] - mean) * rstd * g4.x + b4.x;
    o.y = (ys[1] - mean) * rstd * g4.y + b4.y;
    o.z = (ys[2] - mean) * rstd * g4.z + b4.z;
    o.w = (ys[3] - mean) * rstd * g4.w + b4.w;
    *(float4*)&sp[s * VSA + 4 * tid] = o;
}

// ---------------- Kernel 2: per-batch fused pipeline ----------------
__global__ __launch_bounds__(NT, 3)
void main_kernel(const float* __restrict__ values, const float* __restrict__ h,
                 const float* __restrict__ sp, const float* __restrict__ gamma,
                 const float* __restrict__ beta, float* __restrict__ out)
{
    __shared__ float hpad[SS][PW];          // 21.8 KB
    __shared__ float vpbuf[SS][VSA];        // 20.5 KB
    __shared__ float red[SS][4][2];
    __shared__ int   scorered[4][SS * SS];
    __shared__ float wbuf[SS * SS];

    const int b = blockIdx.x;
    const int tid = threadIdx.x;
    const int lane = tid & 63, wave = tid >> 6;

    // stage zero-padded h
#pragma unroll
    for (int s = 0; s < SS; s++)
        for (int r = tid; r < PW; r += NT)
            hpad[s][r] = (r >= POFF && r <= POFF + 960) ? h[s * HSZ + (r - POFF)] : 0.f;
    __syncthreads();

    // conv + silu for all 5 s; keep ys in registers, one sync for LN partials
    const float* xbase = values + (size_t)b * SS * DD;   // uniform -> s_load path
    float ys[SS][4];
#pragma unroll
    for (int s = 0; s < SS; s++) {
        float acc[4];
        conv4(xbase + s * DD, hpad[s], tid, acc);
        float lsum = 0.f, lsq = 0.f;
#pragma unroll
        for (int j = 0; j < 4; j++) {
            const float y = silu_f(acc[j]);
            ys[s][j] = y; lsum += y; lsq += y * y;
        }
#pragma unroll
        for (int off = 32; off; off >>= 1) {
            lsum += __shfl_down(lsum, off, 64);
            lsq  += __shfl_down(lsq,  off, 64);
        }
        if (lane == 0) { red[s][wave][0] = lsum; red[s][wave][1] = lsq; }
    }
    __syncthreads();

    // LayerNorm epilogue -> vpbuf
    const float4 g4 = *(const float4*)&gamma[4 * tid];
    const float4 b4 = *(const float4*)&beta[4 * tid];
#pragma unroll
    for (int s = 0; s < SS; s++) {
        float s0 = 0.f, s1 = 0.f;
#pragma unroll
        for (int w = 0; w < 4; w++) { s0 += red[s][w][0]; s1 += red[s][w][1]; }
        const float mean = s0 * (1.f / VSA);
        const float rstd = rsqrtf(s1 * (1.f / VSA) - mean * mean + LNE);
        float4 o;
        o.x = (ys[s][0] - mean) * rstd * g4.x + b4.x;
        o.y = (ys[s][1] - mean) * rstd * g4.y + b4.y;
        o.z = (ys[s][2] - mean) * rstd * g4.z + b4.z;
        o.w = (ys[s][3] - mean) * rstd * g4.w + b4.w;
        *(float4*)&vpbuf[s][4 * tid] = o;
    }
    __syncthreads();

    // load vp/sp fragments (float4 per i)
    float vp4[SS][4], sp4[SS][4];
#pragma unroll
    for (int i = 0; i < SS; i++) {
        *(float4*)&vp4[i][0] = *(const float4*)&vpbuf[i][4 * tid];
        *(float4*)&sp4[i][0] = *(const float4*)&sp[i * VSA + 4 * tid];
    }

    // scores via ballot: sign(a)*sign(b) = 1 - 2*[signbits differ] (zeros ~never)
    int neq[SS * SS];
#pragma unroll
    for (int p = 0; p < SS * SS; p++) neq[p] = 0;
#pragma unroll
    for (int jj = 0; jj < 4; jj++) {
        unsigned long long bvi[SS];
#pragma unroll
        for (int i = 0; i < SS; i++) bvi[i] = __ballot(vp4[i][jj] > 0.f);
#pragma unroll
        for (int j = 0; j < SS; j++) {
            const float sjv = sp4[j][jj];
#pragma unroll
            for (int i = 0; i < SS; i++) {
                const unsigned long long bs = __ballot(vp4[i][jj] + sjv > 0.f);
                neq[j * SS + i] += (int)__popcll(bvi[i] ^ bs);
            }
        }
    }
    if (lane == 0) {
#pragma unroll
        for (int p = 0; p < SS * SS; p++) scorered[wave][p] = neq[p];
    }
    __syncthreads();

    // softmax over i per row j (5 threads)
    if (tid < SS) {
        const int j = tid;
        float sc[SS];
#pragma unroll
        for (int i = 0; i < SS; i++) {
            const int nq = scorered[0][j * SS + i] + scorered[1][j * SS + i]
                         + scorered[2][j * SS + i] + scorered[3][j * SS + i];
            sc[i] = 1.f - (2.f / VSA) * (float)nq;
        }
        float m = sc[0];
#pragma unroll
        for (int i = 1; i < SS; i++) m = fmaxf(m, sc[i]);
        float e[SS], ssum = 0.f;
#pragma unroll
        for (int i = 0; i < SS; i++) { e[i] = __expf(sc[i] - m); ssum += e[i]; }
        const float inv = 1.f / ssum;
#pragma unroll
        for (int i = 0; i < SS; i++) wbuf[j * SS + i] = e[i] * inv;
    }
    __syncthreads();

    // out[b][j][t] = silu( (sum_i w[j][i]*vp[i][t]) * sp[j][t] )
    float w[SS * SS];
#pragma unroll
    for (int p = 0; p < SS * SS; p++) w[p] = wbuf[p];

    const size_t base = (size_t)b * SS * VSA + 4 * tid;
#pragma unroll
    for (int j = 0; j < SS; j++) {
        float att[4] = {0.f, 0.f, 0.f, 0.f};
#pragma unroll
        for (int i = 0; i < SS; i++) {
            const float wi = w[j * SS + i];
#pragma unroll
            for (int e = 0; e < 4; e++) att[e] += wi * vp4[i][e];
        }
        float4 o;
        o.x = silu_f(att[0] * sp4[j][0]);
        o.y = silu_f(att[1] * sp4[j][1]);
        o.z = silu_f(att[2] * sp4[j][2]);
        o.w = silu_f(att[3] * sp4[j][3]);
        *(float4*)&out[base + (size_t)j * VSA] = o;
    }
}

extern "C" void kernel_launch(void* const* d_in, const int* in_sizes, int n_in,
                              void* d_out, int out_size, void* d_ws, size_t ws_size,
                              hipStream_t stream) {
    const float* values  = (const float*)d_in[0];
    const float* h       = (const float*)d_in[1];
    const float* symbols = (const float*)d_in[2];
    const float* gamma   = (const float*)d_in[3];
    const float* beta    = (const float*)d_in[4];
    float* out = (float*)d_out;
    float* sp  = (float*)d_ws;   // S*VSA floats = 20 KB

    sp_kernel<<<SS, NT, 0, stream>>>(symbols, h, gamma, beta, sp);
    main_kernel<<<BB, NT, 0, stream>>>(values, h, sp, gamma, beta, out);
}

// Round 3
// 224.708 us; speedup vs baseline: 2.7504x; 1.0239x over previous
//
#include <hip/hip_runtime.h>
#include <math.h>

#define BB   4096
#define SS   5
#define DD   64
#define HSZ  961
#define VSA  1024
#define NT   256
#define LNE  1e-3f

// padded h layout: P[r] = h[r-POFF] for r in [POFF, POFF+960], else 0
#define POFF 64
#define PW   1092   // max index accessed = 1091; PW*4 = 4368 B (16B-aligned rows)

__device__ __forceinline__ float silu_f(float x) { return x / (1.f + __expf(-x)); }

// Register-blocked conv for 4 consecutive outputs t = 4*tid+j, reading the
// sliding h-window from GLOBAL (L1-resident, coalesced dwordx4: 64 lanes x 16B
// descending-contiguous = 1024B/instr). x is block-uniform -> s_load path.
__device__ __forceinline__ void conv4_g(const float* __restrict__ xp,   // 64 uniform floats
                                        const float* __restrict__ hp,   // hpadG + s*PW + base
                                        float acc[4])
{
    float hw[8];
    *(float4*)&hw[0] = *(const float4*)hp;
    acc[0] = acc[1] = acc[2] = acc[3] = 0.f;
#pragma unroll
    for (int c = 0; c < 16; c++) {
        *(float4*)&hw[4] = *(const float4*)(hp + 4 * (c + 1));
        const float x0 = xp[4 * c + 0];
        const float x1 = xp[4 * c + 1];
        const float x2 = xp[4 * c + 2];
        const float x3 = xp[4 * c + 3];
        acc[0] += x0 * hw[4]; acc[0] += x1 * hw[5]; acc[0] += x2 * hw[6]; acc[0] += x3 * hw[7];
        acc[1] += x0 * hw[3]; acc[1] += x1 * hw[4]; acc[1] += x2 * hw[5]; acc[1] += x3 * hw[6];
        acc[2] += x0 * hw[2]; acc[2] += x1 * hw[3]; acc[2] += x2 * hw[4]; acc[2] += x3 * hw[5];
        acc[3] += x0 * hw[1]; acc[3] += x1 * hw[2]; acc[3] += x2 * hw[3]; acc[3] += x3 * hw[4];
        hw[0] = hw[4]; hw[1] = hw[5]; hw[2] = hw[6]; hw[3] = hw[7];
    }
}

// ---- Kernel 1: sp = LN(silu(conv(symbols,h))); also emit zero-padded h ----
__global__ __launch_bounds__(NT)
void sp_kernel(const float* __restrict__ symbols, const float* __restrict__ h,
               const float* __restrict__ gamma, const float* __restrict__ beta,
               float* __restrict__ sp, float* __restrict__ hpadG)
{
    __shared__ float hpad[PW];
    __shared__ float red[4][2];
    const int s = blockIdx.x;
    const int tid = threadIdx.x;
    const int lane = tid & 63, wave = tid >> 6;

    for (int r = tid; r < PW; r += NT) {
        const float v = (r >= POFF && r <= POFF + 960) ? h[s * HSZ + (r - POFF)] : 0.f;
        hpad[r] = v;
        hpadG[s * PW + r] = v;        // padded copy for main_kernel
    }
    __syncthreads();

    const int base = 1020 - 4 * tid;
    float hw[8];
    *(float4*)&hw[0] = *(const float4*)&hpad[base];
    float acc[4] = {0.f, 0.f, 0.f, 0.f};
    const float* xp = symbols + s * DD;
#pragma unroll
    for (int c = 0; c < 16; c++) {
        *(float4*)&hw[4] = *(const float4*)&hpad[base + 4 * (c + 1)];
        const float x0 = xp[4 * c + 0];
        const float x1 = xp[4 * c + 1];
        const float x2 = xp[4 * c + 2];
        const float x3 = xp[4 * c + 3];
        acc[0] += x0 * hw[4]; acc[0] += x1 * hw[5]; acc[0] += x2 * hw[6]; acc[0] += x3 * hw[7];
        acc[1] += x0 * hw[3]; acc[1] += x1 * hw[4]; acc[1] += x2 * hw[5]; acc[1] += x3 * hw[6];
        acc[2] += x0 * hw[2]; acc[2] += x1 * hw[3]; acc[2] += x2 * hw[4]; acc[2] += x3 * hw[5];
        acc[3] += x0 * hw[1]; acc[3] += x1 * hw[2]; acc[3] += x2 * hw[3]; acc[3] += x3 * hw[4];
        hw[0] = hw[4]; hw[1] = hw[5]; hw[2] = hw[6]; hw[3] = hw[7];
    }

    float ys[4];
    float lsum = 0.f, lsq = 0.f;
#pragma unroll
    for (int j = 0; j < 4; j++) {
        ys[j] = silu_f(acc[j]);
        lsum += ys[j]; lsq += ys[j] * ys[j];
    }
#pragma unroll
    for (int off = 32; off; off >>= 1) {
        lsum += __shfl_down(lsum, off, 64);
        lsq  += __shfl_down(lsq,  off, 64);
    }
    if (lane == 0) { red[wave][0] = lsum; red[wave][1] = lsq; }
    __syncthreads();
    float s0 = 0.f, s1 = 0.f;
#pragma unroll
    for (int w = 0; w < 4; w++) { s0 += red[w][0]; s1 += red[w][1]; }
    const float mean = s0 * (1.f / VSA);
    const float rstd = rsqrtf(s1 * (1.f / VSA) - mean * mean + LNE);

    const float4 g4 = *(const float4*)&gamma[4 * tid];
    const float4 b4 = *(const float4*)&beta[4 * tid];
    float4 o;
    o.x = (ys[0] - mean) * rstd * g4.x + b4.x;
    o.y = (ys[1] - mean) * rstd * g4.y + b4.y;
    o.z = (ys[2] - mean) * rstd * g4.z + b4.z;
    o.w = (ys[3] - mean) * rstd * g4.w + b4.w;
    *(float4*)&sp[s * VSA + 4 * tid] = o;
}

// ---------------- Kernel 2: per-batch fused pipeline (near-LDS-free) --------
__global__ __launch_bounds__(NT, 4)
void main_kernel(const float* __restrict__ values, const float* __restrict__ hpadG,
                 const float* __restrict__ sp, const float* __restrict__ gamma,
                 const float* __restrict__ beta, float* __restrict__ out)
{
    __shared__ float red[SS][4][2];
    __shared__ int   scorered[4][SS * SS];
    __shared__ float wbuf[SS * SS];

    const int b = blockIdx.x;
    const int tid = threadIdx.x;
    const int lane = tid & 63, wave = tid >> 6;
    const int base = 1020 - 4 * tid;

    const float* xbase = values + (size_t)b * SS * DD;   // uniform -> s_load path
    float vp4[SS][4];   // conv->silu->LN results, this thread's t = 4*tid+j

    // conv + silu for all 5 s; LN partials to LDS, one sync total
#pragma unroll
    for (int s = 0; s < SS; s++) {
        float acc[4];
        conv4_g(xbase + s * DD, hpadG + s * PW + base, acc);
        float lsum = 0.f, lsq = 0.f;
#pragma unroll
        for (int j = 0; j < 4; j++) {
            const float y = silu_f(acc[j]);
            vp4[s][j] = y; lsum += y; lsq += y * y;
        }
#pragma unroll
        for (int off = 32; off; off >>= 1) {
            lsum += __shfl_down(lsum, off, 64);
            lsq  += __shfl_down(lsq,  off, 64);
        }
        if (lane == 0) { red[s][wave][0] = lsum; red[s][wave][1] = lsq; }
    }
    __syncthreads();

    // LayerNorm epilogue — in registers (no cross-thread vp needed, ever)
    const float4 g4 = *(const float4*)&gamma[4 * tid];
    const float4 b4 = *(const float4*)&beta[4 * tid];
#pragma unroll
    for (int s = 0; s < SS; s++) {
        float s0 = 0.f, s1 = 0.f;
#pragma unroll
        for (int w = 0; w < 4; w++) { s0 += red[s][w][0]; s1 += red[s][w][1]; }
        const float mean = s0 * (1.f / VSA);
        const float rstd = rsqrtf(s1 * (1.f / VSA) - mean * mean + LNE);
        vp4[s][0] = (vp4[s][0] - mean) * rstd * g4.x + b4.x;
        vp4[s][1] = (vp4[s][1] - mean) * rstd * g4.y + b4.y;
        vp4[s][2] = (vp4[s][2] - mean) * rstd * g4.z + b4.z;
        vp4[s][3] = (vp4[s][3] - mean) * rstd * g4.w + b4.w;
    }

    // sp fragments (global, coalesced, L1/L2-hot)
    float sp4[SS][4];
#pragma unroll
    for (int i = 0; i < SS; i++)
        *(float4*)&sp4[i][0] = *(const float4*)&sp[i * VSA + 4 * tid];

    // scores via ballot: sign(a)*sign(b) = 1 - 2*[signbits differ]
    int neq[SS * SS];
#pragma unroll
    for (int p = 0; p < SS * SS; p++) neq[p] = 0;
#pragma unroll
    for (int jj = 0; jj < 4; jj++) {
        unsigned long long bvi[SS];
#pragma unroll
        for (int i = 0; i < SS; i++) bvi[i] = __ballot(vp4[i][jj] > 0.f);
#pragma unroll
        for (int j = 0; j < SS; j++) {
            const float sjv = sp4[j][jj];
#pragma unroll
            for (int i = 0; i < SS; i++) {
                const unsigned long long bs = __ballot(vp4[i][jj] + sjv > 0.f);
                neq[j * SS + i] += (int)__popcll(bvi[i] ^ bs);
            }
        }
    }
    if (lane == 0) {
#pragma unroll
        for (int p = 0; p < SS * SS; p++) scorered[wave][p] = neq[p];
    }
    __syncthreads();

    // softmax over i per row j (5 threads)
    if (tid < SS) {
        const int j = tid;
        float sc[SS];
#pragma unroll
        for (int i = 0; i < SS; i++) {
            const int nq = scorered[0][j * SS + i] + scorered[1][j * SS + i]
                         + scorered[2][j * SS + i] + scorered[3][j * SS + i];
            sc[i] = 1.f - (2.f / VSA) * (float)nq;
        }
        float m = sc[0];
#pragma unroll
        for (int i = 1; i < SS; i++) m = fmaxf(m, sc[i]);
        float e[SS], ssum = 0.f;
#pragma unroll
        for (int i = 0; i < SS; i++) { e[i] = __expf(sc[i] - m); ssum += e[i]; }
        const float inv = 1.f / ssum;
#pragma unroll
        for (int i = 0; i < SS; i++) wbuf[j * SS + i] = e[i] * inv;
    }
    __syncthreads();

    float w[SS * SS];
#pragma unroll
    for (int p = 0; p < SS * SS; p++) w[p] = wbuf[p];

    // out[b][j][t] = silu( (sum_i w[j][i]*vp[i][t]) * sp[j][t] )
    const size_t obase = (size_t)b * SS * VSA + 4 * tid;
#pragma unroll
    for (int j = 0; j < SS; j++) {
        float att[4] = {0.f, 0.f, 0.f, 0.f};
#pragma unroll
        for (int i = 0; i < SS; i++) {
            const float wi = w[j * SS + i];
#pragma unroll
            for (int e = 0; e < 4; e++) att[e] += wi * vp4[i][e];
        }
        float4 o;
        o.x = silu_f(att[0] * sp4[j][0]);
        o.y = silu_f(att[1] * sp4[j][1]);
        o.z = silu_f(att[2] * sp4[j][2]);
        o.w = silu_f(att[3] * sp4[j][3]);
        *(float4*)&out[obase + (size_t)j * VSA] = o;
    }
}

extern "C" void kernel_launch(void* const* d_in, const int* in_sizes, int n_in,
                              void* d_out, int out_size, void* d_ws, size_t ws_size,
                              hipStream_t stream) {
    const float* values  = (const float*)d_in[0];
    const float* h       = (const float*)d_in[1];
    const float* symbols = (const float*)d_in[2];
    const float* gamma   = (const float*)d_in[3];
    const float* beta    = (const float*)d_in[4];
    float* out   = (float*)d_out;
    float* sp    = (float*)d_ws;                 // 5*1024 floats
    float* hpadG = (float*)d_ws + SS * VSA;      // 5*1092 floats (padded h)

    sp_kernel<<<SS, NT, 0, stream>>>(symbols, h, gamma, beta, sp, hpadG);
    main_kernel<<<BB, NT, 0, stream>>>(values, hpadG, sp, gamma, beta, out);
}